// Round 14
// baseline (447.884 us; speedup 1.0000x reference)
//
#include <hip/hip_runtime.h>

#define NF 128
#define NH 128
#define NO 256
#define NG 256

typedef unsigned int   u32;
typedef unsigned short u16;
typedef __attribute__((ext_vector_type(8))) short short8;
typedef __attribute__((ext_vector_type(4))) float floatx4;

__device__ __forceinline__ float bflo(u32 g) { return __uint_as_float(g << 16); }
__device__ __forceinline__ float bfhi(u32 g) { return __uint_as_float(g & 0xffff0000u); }
__device__ __forceinline__ u16 f2bf(float x) {
    u32 u = __float_as_uint(x);
    u += 0x7fffu + ((u >> 16) & 1u);
    return (u16)(u >> 16);
}
__device__ __forceinline__ u32 packbf2(float x, float y) {
    u32 ux = __float_as_uint(x); ux += 0x7fffu + ((ux >> 16) & 1u);
    u32 uy = __float_as_uint(y); uy += 0x7fffu + ((uy >> 16) & 1u);
    return (ux >> 16) | (uy & 0xffff0000u);
}

// ---------------- setup: weight casts (blocks 0..191) + coarse counting (rest) ----------------
// bucket = col >> 8 (256-node buckets, up to 512)

__global__ __launch_bounds__(256) void setup_kernel(const float* __restrict__ W1,
                                                    const float* __restrict__ W2,
                                                    const float* __restrict__ W3,
                                                    u16* __restrict__ Wt1, u16* __restrict__ Wt2,
                                                    u16* __restrict__ Wt3,
                                                    const int* __restrict__ col, int E,
                                                    int* __restrict__ bucketCnt) {
    int b = blockIdx.x;
    int t = threadIdx.x;
    if (b < 192) {
        int idx = b * 256 + t;
        int w = idx >> 14;
        int r = idx & 16383;
        const float* W = (w == 0) ? W1 : (w == 1) ? W2 : W3;
        u16* Wt = (w == 0) ? Wt1 : (w == 1) ? Wt2 : Wt3;
        int k = r >> 7, c = r & 127;
        Wt[c * NF + k] = f2bf(W[r]);
        return;
    }
    __shared__ int h[512];
    h[t] = 0; h[t + 256] = 0;
    __syncthreads();
    int base = (b - 192) * 4096;
    #pragma unroll
    for (int i = 0; i < 16; ++i) {
        int e = base + i * 256 + t;
        if (e < E) atomicAdd(&h[col[e] >> 8], 1);
    }
    __syncthreads();
    if (h[t])       atomicAdd(&bucketCnt[t], h[t]);
    if (h[t + 256]) atomicAdd(&bucketCnt[t + 256], h[t + 256]);
}

// scan 512 bucket counts -> cbase + gcur; also zero pooled (NG*NH floats)
__global__ void scan_buckets(const int* __restrict__ bucketCnt, int* __restrict__ cbase,
                             int* __restrict__ gcur, float* __restrict__ pooled) {
    __shared__ int sh[512];
    int t = threadIdx.x;   // 512 threads
    int v = bucketCnt[t];
    sh[t] = v; __syncthreads();
    for (int d = 1; d < 512; d <<= 1) {
        int x = (t >= d) ? sh[t - d] : 0;
        __syncthreads();
        sh[t] += x;
        __syncthreads();
    }
    cbase[t] = sh[t] - v;
    gcur[t]  = sh[t] - v;
    float4 z = make_float4(0.f, 0.f, 0.f, 0.f);
    float4* p4 = (float4*)pooled;
    #pragma unroll
    for (int i = 0; i < 16; ++i) p4[i * 512 + t] = z;   // 16*512*4 = NG*NH floats
}

// ---------------- phase 1: coarse binning (bucket = col >> 8) ----------------
// packed record: row (17 bits) | (col & 255) << 17

__global__ __launch_bounds__(256) void bin_coarse(const int* __restrict__ row,
                                                  const int* __restrict__ col,
                                                  int* __restrict__ gcur,
                                                  u32* __restrict__ coarse, int E) {
    __shared__ u32 cnt[512];
    __shared__ u32 lcur[512];
    __shared__ u32 gbase[512];
    __shared__ u32 sc[512];
    __shared__ u32 tmp[512];
    __shared__ u32 packed[4096];
    int t = threadIdx.x;
    int base = blockIdx.x * 4096;
    cnt[t] = 0; cnt[t + 256] = 0;
    __syncthreads();

    u32 rv[16], cv[16];
    #pragma unroll
    for (int i = 0; i < 16; ++i) {
        int e = base + i * 256 + t;
        if (e < E) {
            rv[i] = (u32)row[e];
            cv[i] = (u32)col[e];
            atomicAdd(&cnt[cv[i] >> 8], 1u);
        }
    }
    __syncthreads();
    for (int j = t; j < 512; j += 256) sc[j] = cnt[j];
    __syncthreads();
    for (int d = 1; d < 512; d <<= 1) {
        for (int j = t; j < 512; j += 256) tmp[j] = (j >= d) ? sc[j - d] : 0u;
        __syncthreads();
        for (int j = t; j < 512; j += 256) sc[j] += tmp[j];
        __syncthreads();
    }
    u32 total = sc[511];
    for (int j = t; j < 512; j += 256) {
        u32 own = cnt[j];
        u32 excl = sc[j] - own;
        if (own > 0) gbase[j] = (u32)atomicAdd(&gcur[j], (int)own);
        lcur[j] = excl;
        tmp[j]  = excl;    // bucket start within packed
    }
    __syncthreads();

    #pragma unroll
    for (int i = 0; i < 16; ++i) {
        int e = base + i * 256 + t;
        if (e < E) {
            u32 p = atomicAdd(&lcur[cv[i] >> 8], 1u);
            packed[p] = rv[i] | ((cv[i] & 255u) << 17);
        }
    }
    __syncthreads();

    for (u32 i = t; i < total; i += 256) {
        u32 lo = 0, hi = 511;
        while (lo < hi) { u32 mid = (lo + hi + 1) >> 1; if (tmp[mid] <= i) lo = mid; else hi = mid - 1; }
        coarse[gbase[lo] + (i - tmp[lo])] = packed[i];
    }
}

// ---------------- phase 2: per-bucket CSR finalize (256-node buckets) ----------------
// Multi-pass scatter over src ranges of 16K nodes so each dst segment ends up
// src-block-SORTED -> concurrent aggregate waves share L2 working set and
// HBM misses become near-sequential (R8 mechanism, now LDS-resident = cheap).

__global__ __launch_bounds__(256) void build_csr_bucket(const u32* __restrict__ coarse,
                                                        const int* __restrict__ cbase,
                                                        const int* __restrict__ bucketCnt,
                                                        u32* __restrict__ srcs,
                                                        int* __restrict__ deg,
                                                        float* __restrict__ dinv,
                                                        int* __restrict__ offs, int N,
                                                        int npass) {
    __shared__ u32 buf[6144];
    __shared__ u32 hist[256];
    __shared__ u32 scn[256];
    __shared__ u32 cur[256];
    int t = threadIdx.x;
    int b = blockIdx.x;
    int lo = b << 8;
    if (lo >= N) return;
    int cnt  = bucketCnt[b];
    int base = cbase[b];

    hist[t] = 0;
    __syncthreads();
    for (int i = t; i < cnt; i += 256) {
        u32 pk = coarse[base + i];
        if (i < 6144) buf[i] = pk;
        atomicAdd(&hist[pk >> 17], 1u);
    }
    __syncthreads();
    scn[t] = hist[t];
    __syncthreads();
    for (int d = 1; d < 256; d <<= 1) {
        u32 x = (t >= d) ? scn[t - d] : 0u;
        __syncthreads();
        scn[t] += x;
        __syncthreads();
    }
    u32 excl = scn[t] - hist[t];
    cur[t] = excl;
    int node = lo + t;
    if (node < N) {
        deg[node]  = (int)hist[t];
        dinv[node] = rsqrtf((float)hist[t] + 1.0f);
        offs[node] = base + (int)excl;
    }
    __syncthreads();
    // src-range passes: pass p places edges with src>>14 == p (segments end src-sorted)
    for (int p = 0; p < npass; ++p) {
        for (int i = t; i < cnt; i += 256) {
            u32 pk = (i < 6144) ? buf[i] : coarse[base + i];
            u32 s = pk & 0x1ffffu;
            if ((int)(s >> 14) == p) {
                u32 c = pk >> 17;
                u32 pos = atomicAdd(&cur[c], 1u);
                srcs[base + pos] = s;
            }
        }
        __syncthreads();
    }
}

// ---------------- persistent-W MFMA GEMM with register prefetch ----------------

__device__ __forceinline__ void gemm_tile(u16* As, const u16* Wt, const float* dinv,
                                          u16* C, int n, int node0, int t) {
    int wv = t >> 6;
    int l  = t & 63;
    int lr = l & 15;
    int lq = l >> 4;

    floatx4 acc[8];
    #pragma unroll
    for (int c = 0; c < 8; ++c) acc[c] = (floatx4){0.f, 0.f, 0.f, 0.f};

    #pragma unroll
    for (int kk = 0; kk < 4; ++kk) {
        short8 af = *(const short8*)&As[(wv * 16 + lr) * 136 + kk * 32 + lq * 8];
        #pragma unroll
        for (int c = 0; c < 8; ++c) {
            short8 bf = *(const short8*)&Wt[(c * 16 + lr) * 136 + kk * 32 + lq * 8];
            acc[c] = __builtin_amdgcn_mfma_f32_16x16x32_bf16(af, bf, acc[c], 0, 0, 0);
        }
    }

    float* Cs = (float*)As;
    #pragma unroll
    for (int h = 0; h < 2; ++h) {
        __syncthreads();
        if ((wv >> 1) == h) {
            int lrow = (wv & 1) * 16 + lq * 4;
            #pragma unroll
            for (int c = 0; c < 8; ++c)
                #pragma unroll
                for (int r = 0; r < 4; ++r)
                    Cs[(lrow + r) * 132 + c * 16 + lr] = acc[c][r];
        }
        __syncthreads();
        int nd = t >> 3, seg = t & 7;
        int node = node0 + h * 32 + nd;
        if (node < n) {
            float di = dinv[node];
            const float* src = &Cs[nd * 132 + seg * 16];
            u32 o[8];
            #pragma unroll
            for (int i = 0; i < 8; ++i) o[i] = packbf2(di * src[2 * i], di * src[2 * i + 1]);
            uint4* dst = (uint4*)(C + (size_t)node * NH + seg * 16);
            dst[0] = make_uint4(o[0], o[1], o[2], o[3]);
            dst[1] = make_uint4(o[4], o[5], o[6], o[7]);
        }
    }
    __syncthreads();
}

// bf16-input variant (layers 2,3)
__global__ __launch_bounds__(256) void gemm_mfma(const u16* __restrict__ A,
                                                 const u16* __restrict__ Wtg,
                                                 const float* __restrict__ dinv,
                                                 u16* __restrict__ C, int n, int ntiles) {
    __shared__ u16 Wt[128 * 136];
    __shared__ u16 As[64 * 136];
    int t = threadIdx.x;

    const uint4* Wg = (const uint4*)Wtg;
    #pragma unroll
    for (int i = 0; i < 8; ++i) {
        int idx = t + 256 * i;
        int cc = idx >> 4, q = idx & 15;
        *(uint4*)&Wt[cc * 136 + q * 8] = Wg[cc * 16 + q];
    }

    const uint4* Ag = (const uint4*)A;
    uint4 pv[4];
    int tile = blockIdx.x;
    if (tile < ntiles) {
        int node0 = tile * 64;
        #pragma unroll
        for (int i = 0; i < 4; ++i) {
            int idx = t + 256 * i;
            int nd = idx >> 4, q = idx & 15;
            pv[i] = make_uint4(0, 0, 0, 0);
            if (node0 + nd < n) pv[i] = Ag[(size_t)(node0 + nd) * 16 + q];
        }
    }
    for (; tile < ntiles; tile += gridDim.x) {
        #pragma unroll
        for (int i = 0; i < 4; ++i) {
            int idx = t + 256 * i;
            int nd = idx >> 4, q = idx & 15;
            *(uint4*)&As[nd * 136 + q * 8] = pv[i];
        }
        __syncthreads();
        int nxt = tile + gridDim.x;
        if (nxt < ntiles) {
            int node0n = nxt * 64;
            #pragma unroll
            for (int i = 0; i < 4; ++i) {
                int idx = t + 256 * i;
                int nd = idx >> 4, q = idx & 15;
                pv[i] = make_uint4(0, 0, 0, 0);
                if (node0n + nd < n) pv[i] = Ag[(size_t)(node0n + nd) * 16 + q];
            }
        }
        gemm_tile(As, Wt, dinv, C, n, tile * 64, t);
    }
}

// f32-input variant (layer 1, reads x directly)
__global__ __launch_bounds__(256) void gemm_mfma_f32(const float* __restrict__ A,
                                                     const u16* __restrict__ Wtg,
                                                     const float* __restrict__ dinv,
                                                     u16* __restrict__ C, int n, int ntiles) {
    __shared__ u16 Wt[128 * 136];
    __shared__ u16 As[64 * 136];
    int t = threadIdx.x;

    const uint4* Wg = (const uint4*)Wtg;
    #pragma unroll
    for (int i = 0; i < 8; ++i) {
        int idx = t + 256 * i;
        int cc = idx >> 4, q = idx & 15;
        *(uint4*)&Wt[cc * 136 + q * 8] = Wg[cc * 16 + q];
    }

    const float4* Ag = (const float4*)A;
    float4 pv[8];
    int tile = blockIdx.x;
    if (tile < ntiles) {
        int node0 = tile * 64;
        #pragma unroll
        for (int i = 0; i < 8; ++i) {
            int idx = t + 256 * i;
            int nd = idx >> 5, q = idx & 31;
            pv[i] = make_float4(0.f, 0.f, 0.f, 0.f);
            if (node0 + nd < n) pv[i] = Ag[(size_t)(node0 + nd) * 32 + q];
        }
    }
    for (; tile < ntiles; tile += gridDim.x) {
        #pragma unroll
        for (int i = 0; i < 8; ++i) {
            int idx = t + 256 * i;
            int nd = idx >> 5, q = idx & 31;
            uint2 p; p.x = packbf2(pv[i].x, pv[i].y); p.y = packbf2(pv[i].z, pv[i].w);
            *(uint2*)&As[nd * 136 + q * 4] = p;
        }
        __syncthreads();
        int nxt = tile + gridDim.x;
        if (nxt < ntiles) {
            int node0n = nxt * 64;
            #pragma unroll
            for (int i = 0; i < 8; ++i) {
                int idx = t + 256 * i;
                int nd = idx >> 5, q = idx & 31;
                pv[i] = make_float4(0.f, 0.f, 0.f, 0.f);
                if (node0n + nd < n) pv[i] = Ag[(size_t)(node0n + nd) * 32 + q];
            }
        }
        gemm_tile(As, Wt, dinv, C, n, tile * 64, t);
    }
}

// ---------------- fused aggregate: out = relu(dinv*(sum g[src] + g[self]) + b) ----------------
// one node per wave; wave-uniform srcs reads; dword gathers; chunk-16 MLP.

__global__ __launch_bounds__(256) void gcn_aggregate(const u16* __restrict__ gtab,
                                                     const u32* __restrict__ srcs,
                                                     const int* __restrict__ offs,
                                                     const int* __restrict__ deg,
                                                     const float* __restrict__ dinv,
                                                     const float* __restrict__ bias,
                                                     u16* __restrict__ outb, int n) {
    int wv = threadIdx.x >> 6;
    int l  = threadIdx.x & 63;
    int node = blockIdx.x * 4 + wv;
    if (node >= n) return;
    int start = offs[node];
    int end   = start + deg[node];
    const u32* rows = (const u32*)gtab;

    float a0 = 0.f, a1 = 0.f;
    int k = start;
    for (; k + 16 <= end; k += 16) {
        u32 gv[16];
        #pragma unroll
        for (int i = 0; i < 16; ++i) {
            u32 s = srcs[k + i];
            gv[i] = rows[(size_t)s * 64 + l];
        }
        #pragma unroll
        for (int i = 0; i < 16; ++i) { a0 += bflo(gv[i]); a1 += bfhi(gv[i]); }
    }
    for (; k + 4 <= end; k += 4) {
        u32 s0 = srcs[k], s1 = srcs[k + 1], s2 = srcs[k + 2], s3 = srcs[k + 3];
        u32 g0 = rows[(size_t)s0 * 64 + l];
        u32 g1 = rows[(size_t)s1 * 64 + l];
        u32 g2 = rows[(size_t)s2 * 64 + l];
        u32 g3 = rows[(size_t)s3 * 64 + l];
        a0 += bflo(g0) + bflo(g1) + bflo(g2) + bflo(g3);
        a1 += bfhi(g0) + bfhi(g1) + bfhi(g2) + bfhi(g3);
    }
    for (; k < end; ++k) {
        u32 g = rows[(size_t)srcs[k] * 64 + l];
        a0 += bflo(g); a1 += bfhi(g);
    }
    u32 gs = rows[(size_t)node * 64 + l];
    a0 += bflo(gs); a1 += bfhi(gs);
    float di = dinv[node];
    float2 bb = *(const float2*)&bias[l * 2];
    a0 = fmaxf(di * a0 + bb.x, 0.f);
    a1 = fmaxf(di * a1 + bb.y, 0.f);
    ((u32*)outb)[(size_t)node * 64 + l] = packbf2(a0, a1);
}

// ---------------- pool phase A: run-accumulate partial sums (sorted batch) ----------------

__global__ __launch_bounds__(256) void pool_partial(const u16* __restrict__ h,
                                                    const int* __restrict__ batch,
                                                    float* __restrict__ pooled, int n) {
    int t = threadIdx.x;
    int ju = t & 63, sub = t >> 6;
    int bs = blockIdx.x * 128;
    int be = min(bs + 128, n);
    const u32* h32 = (const u32*)h;
    float a0 = 0.f, a1 = 0.f;
    int cur = -1;
    for (int i = bs + sub; i < be; i += 4) {
        int g = batch[i];
        if (g != cur) {
            if (cur >= 0) {
                atomicAdd(&pooled[(size_t)cur * NH + 2 * ju], a0);
                atomicAdd(&pooled[(size_t)cur * NH + 2 * ju + 1], a1);
            }
            a0 = 0.f; a1 = 0.f; cur = g;
        }
        u32 v = h32[(size_t)i * 64 + ju];
        a0 += bflo(v); a1 += bfhi(v);
    }
    if (cur >= 0) {
        atomicAdd(&pooled[(size_t)cur * NH + 2 * ju], a0);
        atomicAdd(&pooled[(size_t)cur * NH + 2 * ju + 1], a1);
    }
}

// ---------------- pool phase B: mean + FC (8 graphs per block) ----------------

__global__ __launch_bounds__(256) void final_fc(const float* __restrict__ pooled,
                                                const int* __restrict__ batch,
                                                const float* __restrict__ Wfc,
                                                const float* __restrict__ bfc,
                                                float* __restrict__ out, int n) {
    int g0 = blockIdx.x * 8;
    int tid = threadIdx.x;
    __shared__ float pr[8][NH];
    __shared__ float invc[8];

    if (tid < 8) {
        int g = g0 + tid;
        int lo = 0, hi = n;
        while (lo < hi) { int m = (lo + hi) >> 1; if (batch[m] < g) lo = m + 1; else hi = m; }
        int start = lo;
        hi = n;
        while (lo < hi) { int m = (lo + hi) >> 1; if (batch[m] < g + 1) lo = m + 1; else hi = m; }
        invc[tid] = 1.0f / fmaxf((float)(lo - start), 1.0f);
    }
    __syncthreads();
    for (int i = tid; i < 8 * NH; i += 256) {
        int gi = i >> 7, j = i & 127;
        pr[gi][j] = pooled[(size_t)(g0 + gi) * NH + j] * invc[gi];
    }
    __syncthreads();

    float bv = bfc[tid];
    float acc[8];
    #pragma unroll
    for (int gi = 0; gi < 8; ++gi) acc[gi] = bv;
    for (int k = 0; k < NH; ++k) {
        float w = Wfc[(size_t)k * NO + tid];
        #pragma unroll
        for (int gi = 0; gi < 8; ++gi) acc[gi] += pr[gi][k] * w;
    }
    #pragma unroll
    for (int gi = 0; gi < 8; ++gi)
        out[(size_t)(g0 + gi) * NO + tid] = acc[gi];
}

// ---------------- launch ----------------

extern "C" void kernel_launch(void* const* d_in, const int* in_sizes, int n_in,
                              void* d_out, int out_size, void* d_ws, size_t ws_size,
                              hipStream_t stream) {
    const float* x   = (const float*)d_in[0];
    const float* W1  = (const float*)d_in[1];
    const float* b1  = (const float*)d_in[2];
    const float* W2  = (const float*)d_in[3];
    const float* b2  = (const float*)d_in[4];
    const float* W3  = (const float*)d_in[5];
    const float* b3  = (const float*)d_in[6];
    const float* Wfc = (const float*)d_in[7];
    const float* bfc = (const float*)d_in[8];
    const int*   ei  = (const int*)d_in[9];
    const int*   bat = (const int*)d_in[10];
    float* out = (float*)d_out;

    const int N = in_sizes[0] / NF;
    const int E = in_sizes[9] / 2;
    const int* rowp = ei;
    const int* colp = ei + E;

    // workspace layout
    char* w = (char*)d_ws;
    u32* srcs    = (u32*)w;                      w += (size_t)E * 4;
    u32* coarse  = (u32*)w;                      w += (size_t)E * 4;
    u16* hA   = (u16*)w;                         w += (size_t)N * NH * 2;
    u16* hB   = (u16*)w;                         w += (size_t)N * NH * 2;
    u16* tmpb = (u16*)w;                         w += (size_t)N * NH * 2;
    u16* Wt1  = (u16*)w;                         w += NF * NH * 2;
    u16* Wt2  = (u16*)w;                         w += NF * NH * 2;
    u16* Wt3  = (u16*)w;                         w += NF * NH * 2;
    float* dinv = (float*)w;                     w += (size_t)N * 4;
    int* degc   = (int*)w;                       w += (size_t)N * 4;
    int* offs   = (int*)w;                       w += (size_t)N * 4;
    float* pooled = (float*)w;                   w += (size_t)NG * NH * 4;  // zeroed in scan_buckets
    int* bucketCnt = (int*)w;                    w += 512 * 4;              // memset region
    int* cbase  = (int*)w;                       w += 512 * 4;
    int* gcur   = (int*)w;                       w += 512 * 4;

    const int TB = 256;
    int ntiles = (N + 63) / 64;
    int gGemmP = (ntiles < 768) ? ntiles : 768;
    int gAgg  = (N + 3) / 4;
    int gPool = (N + 127) / 128;
    int NB = (N + 255) >> 8;             // 256-node buckets (<=512)
    int gBin = (E + 4095) / 4096;
    int nPass = (N + 16383) >> 14;       // src ranges of 16K nodes

    hipMemsetAsync(bucketCnt, 0, 512 * 4, stream);

    // ---- CSR build ----
    setup_kernel<<<192 + gBin, TB, 0, stream>>>(W1, W2, W3, Wt1, Wt2, Wt3, colp, E, bucketCnt);
    scan_buckets<<<1, 512, 0, stream>>>(bucketCnt, cbase, gcur, pooled);
    bin_coarse<<<gBin, TB, 0, stream>>>(rowp, colp, gcur, coarse, E);
    build_csr_bucket<<<NB, TB, 0, stream>>>(coarse, cbase, bucketCnt, srcs, degc, dinv, offs, N, nPass);

    // ---- layer 1 (reads x f32 directly) ----
    gemm_mfma_f32<<<gGemmP, TB, 0, stream>>>(x, Wt1, dinv, tmpb, N, ntiles);
    gcn_aggregate<<<gAgg, TB, 0, stream>>>(tmpb, srcs, offs, degc, dinv, b1, hB, N);

    // ---- layer 2 ----
    gemm_mfma<<<gGemmP, TB, 0, stream>>>(hB, Wt2, dinv, tmpb, N, ntiles);
    gcn_aggregate<<<gAgg, TB, 0, stream>>>(tmpb, srcs, offs, degc, dinv, b2, hA, N);

    // ---- layer 3 ----
    gemm_mfma<<<gGemmP, TB, 0, stream>>>(hA, Wt3, dinv, tmpb, N, ntiles);
    gcn_aggregate<<<gAgg, TB, 0, stream>>>(tmpb, srcs, offs, degc, dinv, b3, hB, N);

    // ---- pool + fc ----
    pool_partial<<<gPool, TB, 0, stream>>>(hB, bat, pooled, N);
    final_fc<<<NG / 8, NO, 0, stream>>>(pooled, bat, Wfc, bfc, out, N);
}

// Round 15
// 431.671 us; speedup vs baseline: 1.0376x; 1.0376x over previous
//
#include <hip/hip_runtime.h>

#define NF 128
#define NH 128
#define NO 256
#define NG 256

typedef unsigned int   u32;
typedef unsigned short u16;
typedef __attribute__((ext_vector_type(8))) short short8;
typedef __attribute__((ext_vector_type(4))) float floatx4;

__device__ __forceinline__ float bflo(u32 g) { return __uint_as_float(g << 16); }
__device__ __forceinline__ float bfhi(u32 g) { return __uint_as_float(g & 0xffff0000u); }
__device__ __forceinline__ u16 f2bf(float x) {
    u32 u = __float_as_uint(x);
    u += 0x7fffu + ((u >> 16) & 1u);
    return (u16)(u >> 16);
}
__device__ __forceinline__ u32 packbf2(float x, float y) {
    u32 ux = __float_as_uint(x); ux += 0x7fffu + ((ux >> 16) & 1u);
    u32 uy = __float_as_uint(y); uy += 0x7fffu + ((uy >> 16) & 1u);
    return (ux >> 16) | (uy & 0xffff0000u);
}

// ---------------- setup: weight casts (blocks 0..191) + coarse counting (rest) ----------------
// bucket = col >> 8 (256-node buckets, up to 512)

__global__ __launch_bounds__(256) void setup_kernel(const float* __restrict__ W1,
                                                    const float* __restrict__ W2,
                                                    const float* __restrict__ W3,
                                                    u16* __restrict__ Wt1, u16* __restrict__ Wt2,
                                                    u16* __restrict__ Wt3,
                                                    const int* __restrict__ col, int E,
                                                    int* __restrict__ bucketCnt) {
    int b = blockIdx.x;
    int t = threadIdx.x;
    if (b < 192) {
        int idx = b * 256 + t;
        int w = idx >> 14;
        int r = idx & 16383;
        const float* W = (w == 0) ? W1 : (w == 1) ? W2 : W3;
        u16* Wt = (w == 0) ? Wt1 : (w == 1) ? Wt2 : Wt3;
        int k = r >> 7, c = r & 127;
        Wt[c * NF + k] = f2bf(W[r]);
        return;
    }
    __shared__ int h[512];
    h[t] = 0; h[t + 256] = 0;
    __syncthreads();
    int base = (b - 192) * 4096;
    #pragma unroll
    for (int i = 0; i < 16; ++i) {
        int e = base + i * 256 + t;
        if (e < E) atomicAdd(&h[col[e] >> 8], 1);
    }
    __syncthreads();
    if (h[t])       atomicAdd(&bucketCnt[t], h[t]);
    if (h[t + 256]) atomicAdd(&bucketCnt[t + 256], h[t + 256]);
}

// scan 512 bucket counts -> cbase + gcur; also zero pooled (NG*NH floats)
__global__ void scan_buckets(const int* __restrict__ bucketCnt, int* __restrict__ cbase,
                             int* __restrict__ gcur, float* __restrict__ pooled) {
    __shared__ int sh[512];
    int t = threadIdx.x;   // 512 threads
    int v = bucketCnt[t];
    sh[t] = v; __syncthreads();
    for (int d = 1; d < 512; d <<= 1) {
        int x = (t >= d) ? sh[t - d] : 0;
        __syncthreads();
        sh[t] += x;
        __syncthreads();
    }
    cbase[t] = sh[t] - v;
    gcur[t]  = sh[t] - v;
    float4 z = make_float4(0.f, 0.f, 0.f, 0.f);
    float4* p4 = (float4*)pooled;
    #pragma unroll
    for (int i = 0; i < 16; ++i) p4[i * 512 + t] = z;   // 16*512*4 = NG*NH floats
}

// ---------------- phase 1: coarse binning (bucket = col >> 8) ----------------
// packed record: row (17 bits) | (col & 255) << 17

__global__ __launch_bounds__(256) void bin_coarse(const int* __restrict__ row,
                                                  const int* __restrict__ col,
                                                  int* __restrict__ gcur,
                                                  u32* __restrict__ coarse, int E) {
    __shared__ u32 cnt[512];
    __shared__ u32 lcur[512];
    __shared__ u32 gbase[512];
    __shared__ u32 sc[512];
    __shared__ u32 tmp[512];
    __shared__ u32 packed[4096];
    int t = threadIdx.x;
    int base = blockIdx.x * 4096;
    cnt[t] = 0; cnt[t + 256] = 0;
    __syncthreads();

    u32 rv[16], cv[16];
    #pragma unroll
    for (int i = 0; i < 16; ++i) {
        int e = base + i * 256 + t;
        if (e < E) {
            rv[i] = (u32)row[e];
            cv[i] = (u32)col[e];
            atomicAdd(&cnt[cv[i] >> 8], 1u);
        }
    }
    __syncthreads();
    for (int j = t; j < 512; j += 256) sc[j] = cnt[j];
    __syncthreads();
    for (int d = 1; d < 512; d <<= 1) {
        for (int j = t; j < 512; j += 256) tmp[j] = (j >= d) ? sc[j - d] : 0u;
        __syncthreads();
        for (int j = t; j < 512; j += 256) sc[j] += tmp[j];
        __syncthreads();
    }
    u32 total = sc[511];
    for (int j = t; j < 512; j += 256) {
        u32 own = cnt[j];
        u32 excl = sc[j] - own;
        if (own > 0) gbase[j] = (u32)atomicAdd(&gcur[j], (int)own);
        lcur[j] = excl;
        tmp[j]  = excl;    // bucket start within packed
    }
    __syncthreads();

    #pragma unroll
    for (int i = 0; i < 16; ++i) {
        int e = base + i * 256 + t;
        if (e < E) {
            u32 p = atomicAdd(&lcur[cv[i] >> 8], 1u);
            packed[p] = rv[i] | ((cv[i] & 255u) << 17);
        }
    }
    __syncthreads();

    for (u32 i = t; i < total; i += 256) {
        u32 lo = 0, hi = 511;
        while (lo < hi) { u32 mid = (lo + hi + 1) >> 1; if (tmp[mid] <= i) lo = mid; else hi = mid - 1; }
        coarse[gbase[lo] + (i - tmp[lo])] = packed[i];
    }
}

// ---------------- phase 2: per-bucket CSR finalize (256-node buckets, single-pass scatter) ----------------

__global__ __launch_bounds__(256) void build_csr_bucket(const u32* __restrict__ coarse,
                                                        const int* __restrict__ cbase,
                                                        const int* __restrict__ bucketCnt,
                                                        u32* __restrict__ srcs,
                                                        int* __restrict__ deg,
                                                        float* __restrict__ dinv,
                                                        int* __restrict__ offs, int N) {
    __shared__ u32 buf[6144];
    __shared__ u32 hist[256];
    __shared__ u32 scn[256];
    __shared__ u32 cur[256];
    int t = threadIdx.x;
    int b = blockIdx.x;
    int lo = b << 8;
    if (lo >= N) return;
    int cnt  = bucketCnt[b];
    int base = cbase[b];

    hist[t] = 0;
    __syncthreads();
    for (int i = t; i < cnt; i += 256) {
        u32 pk = coarse[base + i];
        if (i < 6144) buf[i] = pk;
        atomicAdd(&hist[pk >> 17], 1u);
    }
    __syncthreads();
    scn[t] = hist[t];
    __syncthreads();
    for (int d = 1; d < 256; d <<= 1) {
        u32 x = (t >= d) ? scn[t - d] : 0u;
        __syncthreads();
        scn[t] += x;
        __syncthreads();
    }
    u32 excl = scn[t] - hist[t];
    cur[t] = excl;
    int node = lo + t;
    if (node < N) {
        deg[node]  = (int)hist[t];
        dinv[node] = rsqrtf((float)hist[t] + 1.0f);
        offs[node] = base + (int)excl;
    }
    __syncthreads();
    for (int i = t; i < cnt; i += 256) {
        u32 pk = (i < 6144) ? buf[i] : coarse[base + i];
        u32 c = pk >> 17;
        u32 p = atomicAdd(&cur[c], 1u);
        srcs[base + p] = pk & 0x1ffffu;
    }
}

// ---------------- persistent-W MFMA GEMM with register prefetch ----------------

__device__ __forceinline__ void gemm_tile(u16* As, const u16* Wt, const float* dinv,
                                          u16* C, int n, int node0, int t) {
    int wv = t >> 6;
    int l  = t & 63;
    int lr = l & 15;
    int lq = l >> 4;

    floatx4 acc[8];
    #pragma unroll
    for (int c = 0; c < 8; ++c) acc[c] = (floatx4){0.f, 0.f, 0.f, 0.f};

    #pragma unroll
    for (int kk = 0; kk < 4; ++kk) {
        short8 af = *(const short8*)&As[(wv * 16 + lr) * 136 + kk * 32 + lq * 8];
        #pragma unroll
        for (int c = 0; c < 8; ++c) {
            short8 bf = *(const short8*)&Wt[(c * 16 + lr) * 136 + kk * 32 + lq * 8];
            acc[c] = __builtin_amdgcn_mfma_f32_16x16x32_bf16(af, bf, acc[c], 0, 0, 0);
        }
    }

    float* Cs = (float*)As;
    #pragma unroll
    for (int h = 0; h < 2; ++h) {
        __syncthreads();
        if ((wv >> 1) == h) {
            int lrow = (wv & 1) * 16 + lq * 4;
            #pragma unroll
            for (int c = 0; c < 8; ++c)
                #pragma unroll
                for (int r = 0; r < 4; ++r)
                    Cs[(lrow + r) * 132 + c * 16 + lr] = acc[c][r];
        }
        __syncthreads();
        int nd = t >> 3, seg = t & 7;
        int node = node0 + h * 32 + nd;
        if (node < n) {
            float di = dinv[node];
            const float* src = &Cs[nd * 132 + seg * 16];
            u32 o[8];
            #pragma unroll
            for (int i = 0; i < 8; ++i) o[i] = packbf2(di * src[2 * i], di * src[2 * i + 1]);
            uint4* dst = (uint4*)(C + (size_t)node * NH + seg * 16);
            dst[0] = make_uint4(o[0], o[1], o[2], o[3]);
            dst[1] = make_uint4(o[4], o[5], o[6], o[7]);
        }
    }
    __syncthreads();
}

// bf16-input variant (layers 2,3)
__global__ __launch_bounds__(256) void gemm_mfma(const u16* __restrict__ A,
                                                 const u16* __restrict__ Wtg,
                                                 const float* __restrict__ dinv,
                                                 u16* __restrict__ C, int n, int ntiles) {
    __shared__ u16 Wt[128 * 136];
    __shared__ u16 As[64 * 136];
    int t = threadIdx.x;

    const uint4* Wg = (const uint4*)Wtg;
    #pragma unroll
    for (int i = 0; i < 8; ++i) {
        int idx = t + 256 * i;
        int cc = idx >> 4, q = idx & 15;
        *(uint4*)&Wt[cc * 136 + q * 8] = Wg[cc * 16 + q];
    }

    const uint4* Ag = (const uint4*)A;
    uint4 pv[4];
    int tile = blockIdx.x;
    if (tile < ntiles) {
        int node0 = tile * 64;
        #pragma unroll
        for (int i = 0; i < 4; ++i) {
            int idx = t + 256 * i;
            int nd = idx >> 4, q = idx & 15;
            pv[i] = make_uint4(0, 0, 0, 0);
            if (node0 + nd < n) pv[i] = Ag[(size_t)(node0 + nd) * 16 + q];
        }
    }
    for (; tile < ntiles; tile += gridDim.x) {
        #pragma unroll
        for (int i = 0; i < 4; ++i) {
            int idx = t + 256 * i;
            int nd = idx >> 4, q = idx & 15;
            *(uint4*)&As[nd * 136 + q * 8] = pv[i];
        }
        __syncthreads();
        int nxt = tile + gridDim.x;
        if (nxt < ntiles) {
            int node0n = nxt * 64;
            #pragma unroll
            for (int i = 0; i < 4; ++i) {
                int idx = t + 256 * i;
                int nd = idx >> 4, q = idx & 15;
                pv[i] = make_uint4(0, 0, 0, 0);
                if (node0n + nd < n) pv[i] = Ag[(size_t)(node0n + nd) * 16 + q];
            }
        }
        gemm_tile(As, Wt, dinv, C, n, tile * 64, t);
    }
}

// f32-input variant (layer 1, reads x directly)
__global__ __launch_bounds__(256) void gemm_mfma_f32(const float* __restrict__ A,
                                                     const u16* __restrict__ Wtg,
                                                     const float* __restrict__ dinv,
                                                     u16* __restrict__ C, int n, int ntiles) {
    __shared__ u16 Wt[128 * 136];
    __shared__ u16 As[64 * 136];
    int t = threadIdx.x;

    const uint4* Wg = (const uint4*)Wtg;
    #pragma unroll
    for (int i = 0; i < 8; ++i) {
        int idx = t + 256 * i;
        int cc = idx >> 4, q = idx & 15;
        *(uint4*)&Wt[cc * 136 + q * 8] = Wg[cc * 16 + q];
    }

    const float4* Ag = (const float4*)A;
    float4 pv[8];
    int tile = blockIdx.x;
    if (tile < ntiles) {
        int node0 = tile * 64;
        #pragma unroll
        for (int i = 0; i < 8; ++i) {
            int idx = t + 256 * i;
            int nd = idx >> 5, q = idx & 31;
            pv[i] = make_float4(0.f, 0.f, 0.f, 0.f);
            if (node0 + nd < n) pv[i] = Ag[(size_t)(node0 + nd) * 32 + q];
        }
    }
    for (; tile < ntiles; tile += gridDim.x) {
        #pragma unroll
        for (int i = 0; i < 8; ++i) {
            int idx = t + 256 * i;
            int nd = idx >> 5, q = idx & 31;
            uint2 p; p.x = packbf2(pv[i].x, pv[i].y); p.y = packbf2(pv[i].z, pv[i].w);
            *(uint2*)&As[nd * 136 + q * 4] = p;
        }
        __syncthreads();
        int nxt = tile + gridDim.x;
        if (nxt < ntiles) {
            int node0n = nxt * 64;
            #pragma unroll
            for (int i = 0; i < 8; ++i) {
                int idx = t + 256 * i;
                int nd = idx >> 5, q = idx & 31;
                pv[i] = make_float4(0.f, 0.f, 0.f, 0.f);
                if (node0n + nd < n) pv[i] = Ag[(size_t)(node0n + nd) * 32 + q];
            }
        }
        gemm_tile(As, Wt, dinv, C, n, tile * 64, t);
    }
}

// ---------------- fused aggregate: out = relu(dinv*(sum g[src] + g[self]) + b) ----------------
// one node per wave; wave-uniform srcs reads; dword gathers; chunk-16 MLP.

__global__ __launch_bounds__(256) void gcn_aggregate(const u16* __restrict__ gtab,
                                                     const u32* __restrict__ srcs,
                                                     const int* __restrict__ offs,
                                                     const int* __restrict__ deg,
                                                     const float* __restrict__ dinv,
                                                     const float* __restrict__ bias,
                                                     u16* __restrict__ outb, int n) {
    int wv = threadIdx.x >> 6;
    int l  = threadIdx.x & 63;
    int node = blockIdx.x * 4 + wv;
    if (node >= n) return;
    int start = offs[node];
    int end   = start + deg[node];
    const u32* rows = (const u32*)gtab;

    float a0 = 0.f, a1 = 0.f;
    int k = start;
    for (; k + 16 <= end; k += 16) {
        u32 gv[16];
        #pragma unroll
        for (int i = 0; i < 16; ++i) {
            u32 s = srcs[k + i];
            gv[i] = rows[(size_t)s * 64 + l];
        }
        #pragma unroll
        for (int i = 0; i < 16; ++i) { a0 += bflo(gv[i]); a1 += bfhi(gv[i]); }
    }
    for (; k + 4 <= end; k += 4) {
        u32 s0 = srcs[k], s1 = srcs[k + 1], s2 = srcs[k + 2], s3 = srcs[k + 3];
        u32 g0 = rows[(size_t)s0 * 64 + l];
        u32 g1 = rows[(size_t)s1 * 64 + l];
        u32 g2 = rows[(size_t)s2 * 64 + l];
        u32 g3 = rows[(size_t)s3 * 64 + l];
        a0 += bflo(g0) + bflo(g1) + bflo(g2) + bflo(g3);
        a1 += bfhi(g0) + bfhi(g1) + bfhi(g2) + bfhi(g3);
    }
    for (; k < end; ++k) {
        u32 g = rows[(size_t)srcs[k] * 64 + l];
        a0 += bflo(g); a1 += bfhi(g);
    }
    u32 gs = rows[(size_t)node * 64 + l];
    a0 += bflo(gs); a1 += bfhi(gs);
    float di = dinv[node];
    float2 bb = *(const float2*)&bias[l * 2];
    a0 = fmaxf(di * a0 + bb.x, 0.f);
    a1 = fmaxf(di * a1 + bb.y, 0.f);
    ((u32*)outb)[(size_t)node * 64 + l] = packbf2(a0, a1);
}

// ---------------- pool phase A: run-accumulate partial sums (sorted batch) ----------------

__global__ __launch_bounds__(256) void pool_partial(const u16* __restrict__ h,
                                                    const int* __restrict__ batch,
                                                    float* __restrict__ pooled, int n) {
    int t = threadIdx.x;
    int ju = t & 63, sub = t >> 6;
    int bs = blockIdx.x * 128;
    int be = min(bs + 128, n);
    const u32* h32 = (const u32*)h;
    float a0 = 0.f, a1 = 0.f;
    int cur = -1;
    for (int i = bs + sub; i < be; i += 4) {
        int g = batch[i];
        if (g != cur) {
            if (cur >= 0) {
                atomicAdd(&pooled[(size_t)cur * NH + 2 * ju], a0);
                atomicAdd(&pooled[(size_t)cur * NH + 2 * ju + 1], a1);
            }
            a0 = 0.f; a1 = 0.f; cur = g;
        }
        u32 v = h32[(size_t)i * 64 + ju];
        a0 += bflo(v); a1 += bfhi(v);
    }
    if (cur >= 0) {
        atomicAdd(&pooled[(size_t)cur * NH + 2 * ju], a0);
        atomicAdd(&pooled[(size_t)cur * NH + 2 * ju + 1], a1);
    }
}

// ---------------- pool phase B: mean + FC (8 graphs per block) ----------------

__global__ __launch_bounds__(256) void final_fc(const float* __restrict__ pooled,
                                                const int* __restrict__ batch,
                                                const float* __restrict__ Wfc,
                                                const float* __restrict__ bfc,
                                                float* __restrict__ out, int n) {
    int g0 = blockIdx.x * 8;
    int tid = threadIdx.x;
    __shared__ float pr[8][NH];
    __shared__ float invc[8];

    if (tid < 8) {
        int g = g0 + tid;
        int lo = 0, hi = n;
        while (lo < hi) { int m = (lo + hi) >> 1; if (batch[m] < g) lo = m + 1; else hi = m; }
        int start = lo;
        hi = n;
        while (lo < hi) { int m = (lo + hi) >> 1; if (batch[m] < g + 1) lo = m + 1; else hi = m; }
        invc[tid] = 1.0f / fmaxf((float)(lo - start), 1.0f);
    }
    __syncthreads();
    for (int i = tid; i < 8 * NH; i += 256) {
        int gi = i >> 7, j = i & 127;
        pr[gi][j] = pooled[(size_t)(g0 + gi) * NH + j] * invc[gi];
    }
    __syncthreads();

    float bv = bfc[tid];
    float acc[8];
    #pragma unroll
    for (int gi = 0; gi < 8; ++gi) acc[gi] = bv;
    for (int k = 0; k < NH; ++k) {
        float w = Wfc[(size_t)k * NO + tid];
        #pragma unroll
        for (int gi = 0; gi < 8; ++gi) acc[gi] += pr[gi][k] * w;
    }
    #pragma unroll
    for (int gi = 0; gi < 8; ++gi)
        out[(size_t)(g0 + gi) * NO + tid] = acc[gi];
}

// ---------------- launch ----------------

extern "C" void kernel_launch(void* const* d_in, const int* in_sizes, int n_in,
                              void* d_out, int out_size, void* d_ws, size_t ws_size,
                              hipStream_t stream) {
    const float* x   = (const float*)d_in[0];
    const float* W1  = (const float*)d_in[1];
    const float* b1  = (const float*)d_in[2];
    const float* W2  = (const float*)d_in[3];
    const float* b2  = (const float*)d_in[4];
    const float* W3  = (const float*)d_in[5];
    const float* b3  = (const float*)d_in[6];
    const float* Wfc = (const float*)d_in[7];
    const float* bfc = (const float*)d_in[8];
    const int*   ei  = (const int*)d_in[9];
    const int*   bat = (const int*)d_in[10];
    float* out = (float*)d_out;

    const int N = in_sizes[0] / NF;
    const int E = in_sizes[9] / 2;
    const int* rowp = ei;
    const int* colp = ei + E;

    // workspace layout
    char* w = (char*)d_ws;
    u32* srcs    = (u32*)w;                      w += (size_t)E * 4;
    u32* coarse  = (u32*)w;                      w += (size_t)E * 4;
    u16* hA   = (u16*)w;                         w += (size_t)N * NH * 2;
    u16* hB   = (u16*)w;                         w += (size_t)N * NH * 2;
    u16* tmpb = (u16*)w;                         w += (size_t)N * NH * 2;
    u16* Wt1  = (u16*)w;                         w += NF * NH * 2;
    u16* Wt2  = (u16*)w;                         w += NF * NH * 2;
    u16* Wt3  = (u16*)w;                         w += NF * NH * 2;
    float* dinv = (float*)w;                     w += (size_t)N * 4;
    int* degc   = (int*)w;                       w += (size_t)N * 4;
    int* offs   = (int*)w;                       w += (size_t)N * 4;
    float* pooled = (float*)w;                   w += (size_t)NG * NH * 4;  // zeroed in scan_buckets
    int* bucketCnt = (int*)w;                    w += 512 * 4;              // memset region
    int* cbase  = (int*)w;                       w += 512 * 4;
    int* gcur   = (int*)w;                       w += 512 * 4;

    const int TB = 256;
    int ntiles = (N + 63) / 64;
    int gGemmP = (ntiles < 768) ? ntiles : 768;
    int gAgg  = (N + 3) / 4;
    int gPool = (N + 127) / 128;
    int NB = (N + 255) >> 8;             // 256-node buckets (<=512)
    int gBin = (E + 4095) / 4096;

    hipMemsetAsync(bucketCnt, 0, 512 * 4, stream);

    // ---- CSR build ----
    setup_kernel<<<192 + gBin, TB, 0, stream>>>(W1, W2, W3, Wt1, Wt2, Wt3, colp, E, bucketCnt);
    scan_buckets<<<1, 512, 0, stream>>>(bucketCnt, cbase, gcur, pooled);
    bin_coarse<<<gBin, TB, 0, stream>>>(rowp, colp, gcur, coarse, E);
    build_csr_bucket<<<NB, TB, 0, stream>>>(coarse, cbase, bucketCnt, srcs, degc, dinv, offs, N);

    // ---- layer 1 (reads x f32 directly) ----
    gemm_mfma_f32<<<gGemmP, TB, 0, stream>>>(x, Wt1, dinv, tmpb, N, ntiles);
    gcn_aggregate<<<gAgg, TB, 0, stream>>>(tmpb, srcs, offs, degc, dinv, b1, hB, N);

    // ---- layer 2 ----
    gemm_mfma<<<gGemmP, TB, 0, stream>>>(hB, Wt2, dinv, tmpb, N, ntiles);
    gcn_aggregate<<<gAgg, TB, 0, stream>>>(tmpb, srcs, offs, degc, dinv, b2, hA, N);

    // ---- layer 3 ----
    gemm_mfma<<<gGemmP, TB, 0, stream>>>(hA, Wt3, dinv, tmpb, N, ntiles);
    gcn_aggregate<<<gAgg, TB, 0, stream>>>(tmpb, srcs, offs, degc, dinv, b3, hB, N);

    // ---- pool + fc ----
    pool_partial<<<gPool, TB, 0, stream>>>(hB, bat, pooled, N);
    final_fc<<<NG / 8, NO, 0, stream>>>(pooled, bat, Wfc, bfc, out, N);
}